// Round 2
// baseline (258.359 us; speedup 1.0000x reference)
//
#include <hip/hip_runtime.h>
#include <hip/hip_bf16.h>

#define D 64
#define RSHIFT 9             // 512 nodes per dst-bucket
#define BNODES 512
#define MAXB 256             // >= nb = ceil(100000/512) = 196
#define BCAP 10240           // per-bucket edge capacity (mean 8192, sigma ~90)
#define SCAP 14336           // per-bucket PADDED ssrc capacity (BCAP + 512*7 pad, rounded to 512)
#define OCT_SHIFT 14         // src-octant granularity: 16384 nodes -> ~2MB G window (L2-fit)
#define NOCT 8
#define FH 72                // LDS row stride (bf16): 144B, 4-bank skew per row

typedef unsigned short ushort_t;
typedef unsigned int uint_t;
typedef short short8 __attribute__((ext_vector_type(8)));   // 8 bf16 MFMA frag
typedef float floatx4 __attribute__((ext_vector_type(4)));  // MFMA C/D frag

__device__ inline uint_t pk_bf16(float x, float y) {
    uint_t ux = __float_as_uint(x); ux = ux + 0x7fffu + ((ux >> 16) & 1u);
    uint_t uy = __float_as_uint(y); uy = uy + 0x7fffu + ((uy >> 16) & 1u);
    return (ux >> 16) | (uy & 0xffff0000u);
}
__device__ inline ushort_t rnd_bf16(float x) {
    uint_t u = __float_as_uint(x); u = u + 0x7fffu + ((u >> 16) & 1u);
    return (ushort_t)(u >> 16);
}

// ---------------- stage 1: bucket edges by dst range ----------------
// Packed entry: (src << 9) | (dst & 511). NO per-edge global atomics (R4).
__global__ __launch_bounds__(256) void k_bucket(const int* __restrict__ src,
                                                const int* __restrict__ dst,
                                                int* __restrict__ bcur,
                                                int* __restrict__ ebuf,
                                                int E, int nb) {
    __shared__ int lcnt[MAXB];
    __shared__ int lbase[MAXB];
    int t = threadIdx.x;
    lcnt[t] = 0;
    __syncthreads();
    int base = blockIdx.x * 2048 + t * 8;
    int sv[8], dv[8], sl[8];
    if (base + 7 < E) {
        int4 a0 = *(const int4*)(src + base);
        int4 a1 = *(const int4*)(src + base + 4);
        int4 b0 = *(const int4*)(dst + base);
        int4 b1 = *(const int4*)(dst + base + 4);
        sv[0]=a0.x; sv[1]=a0.y; sv[2]=a0.z; sv[3]=a0.w;
        sv[4]=a1.x; sv[5]=a1.y; sv[6]=a1.z; sv[7]=a1.w;
        dv[0]=b0.x; dv[1]=b0.y; dv[2]=b0.z; dv[3]=b0.w;
        dv[4]=b1.x; dv[5]=b1.y; dv[6]=b1.z; dv[7]=b1.w;
    } else {
        #pragma unroll
        for (int j = 0; j < 8; ++j) {
            dv[j] = (base + j < E) ? dst[base + j] : -1;
            sv[j] = (base + j < E) ? src[base + j] : 0;
        }
    }
    #pragma unroll
    for (int j = 0; j < 8; ++j) {
        if (dv[j] >= 0) {
            int b = dv[j] >> RSHIFT;
            sl[j] = atomicAdd(&lcnt[b], 1);   // LDS atomic only
        }
    }
    __syncthreads();
    if (t < nb) { int c = lcnt[t]; if (c) lbase[t] = atomicAdd(&bcur[t], c); }
    __syncthreads();
    #pragma unroll
    for (int j = 0; j < 8; ++j) {
        if (dv[j] >= 0) {
            int b = dv[j] >> RSHIFT;
            int slot = lbase[b] + sl[j];
            if (slot < BCAP)
                ebuf[(size_t)b * BCAP + slot] = (sv[j] << RSHIFT) | (dv[j] & (BNODES - 1));
        }
    }
}

// ---------------- stage 2: per-bucket CSR build, all atomics in LDS -------
// New in R1: (a) per-bucket fixed ssrc region (b*SCAP) -> no cross-bucket
// prefix; (b) per-node segments padded to x8 (pads -> zero row N) -> uniform
// gather loop, int4 index loads; (c) edges scattered in 8 src-octant passes
// so every node's list is walked in ascending-src-window order -> the whole
// grid reads a ~2MB G window at a time (L2-resident). Edges staged in LDS
// so the 8 passes re-scan LDS, not L2.
__global__ __launch_bounds__(256) void k_csr(const int* __restrict__ ebuf,
                                             const int* __restrict__ bcur,
                                             int2* __restrict__ rowse,
                                             int* __restrict__ ssrc,
                                             float* __restrict__ dis,
                                             int N, int nb) {
    __shared__ int sseg[BCAP];        // 40 KB edge stage
    __shared__ int lcnt[BNODES];
    __shared__ int lcur[BNODES];
    __shared__ int sums[256];
    int b = blockIdx.x;
    int t = threadIdx.x;
    int n = bcur[b];
    if (n > BCAP) n = BCAP;
    int node0 = b << RSHIFT;
    #pragma unroll
    for (int i = t; i < BNODES; i += 256) lcnt[i] = 0;
    __syncthreads();
    const int* seg = ebuf + (size_t)b * BCAP;
    // count + stage edges into LDS
    for (int i = t * 4; i < n; i += 1024) {
        if (i + 3 < n) {
            int4 e = *(const int4*)(seg + i);
            *(int4*)(sseg + i) = e;
            atomicAdd(&lcnt[e.x & (BNODES - 1)], 1);
            atomicAdd(&lcnt[e.y & (BNODES - 1)], 1);
            atomicAdd(&lcnt[e.z & (BNODES - 1)], 1);
            atomicAdd(&lcnt[e.w & (BNODES - 1)], 1);
        } else {
            for (int j = 0; j < 4 && i + j < n; ++j) {
                int e = seg[i + j];
                sseg[i + j] = e;
                atomicAdd(&lcnt[e & (BNODES - 1)], 1);
            }
        }
    }
    __syncthreads();
    int idx = t * 2;
    int v0 = lcnt[idx], v1 = lcnt[idx + 1];
    int p0 = (v0 + 7) & ~7;           // padded lengths
    int p1 = (v1 + 7) & ~7;
    int s = p0 + p1;
    sums[t] = s;
    __syncthreads();
    for (int off = 1; off < 256; off <<= 1) {
        int x = (t >= off) ? sums[t - off] : 0;
        __syncthreads();
        sums[t] += x;
        __syncthreads();
    }
    int run = sums[t] - s;
    int beg0 = b * SCAP + run;
    int beg1 = beg0 + p0;
    lcur[idx] = beg0;
    lcur[idx + 1] = beg1;
    int node = node0 + idx;
    if (node < N)     { rowse[node]     = make_int2(beg0, beg0 + p0); dis[node]     = rsqrtf((float)(v0 + 1)); }
    if (node + 1 < N) { rowse[node + 1] = make_int2(beg1, beg1 + p1); dis[node + 1] = rsqrtf((float)(v1 + 1)); }
    __syncthreads();
    // scatter in 8 src-octant passes (LDS re-scan; barrier keeps octant order)
    for (int oc = 0; oc < NOCT; ++oc) {
        for (int i = t; i < n; i += 256) {
            int e = sseg[i];
            int sv = e >> RSHIFT;
            if ((sv >> OCT_SHIFT) == oc) {
                int p = atomicAdd(&lcur[e & (BNODES - 1)], 1);
                ssrc[p] = sv;
            }
        }
        __syncthreads();
    }
    // fill pads with zero-row index N
    for (int k = v0; k < p0; ++k) ssrc[beg0 + k] = N;
    for (int k = v1; k < p1; ++k) ssrc[beg1 + k] = N;
}

// stage W^T as bf16 into LDS: wt[n][k] = bf16(W[k][n]) (validated R10)
__device__ __forceinline__ void stage_wt(const float* __restrict__ W,
                                         ushort_t* __restrict__ wt, int t) {
    const float4* W4 = (const float4*)W;
    for (int i = t; i < 1024; i += 256) {
        float4 w4 = W4[i];
        int k = i >> 4, n0 = (i & 15) * 4;
        wt[(n0 + 0) * FH + k] = rnd_bf16(w4.x);
        wt[(n0 + 1) * FH + k] = rnd_bf16(w4.y);
        wt[(n0 + 2) * FH + k] = rnd_bf16(w4.z);
        wt[(n0 + 3) * FH + k] = rnd_bf16(w4.w);
    }
}

// ---------------- layer-0 GEMM via MFMA: G = bf16((x@W)*dis) -------------
__global__ __launch_bounds__(256) void k_gemm0(const float* __restrict__ x,
                                               const float* __restrict__ W,
                                               const float* __restrict__ dis,
                                               ushort_t* __restrict__ G, int N) {
    __shared__ ushort_t wt[64 * FH];
    int t = threadIdx.x;
    stage_wt(W, wt, t);
    __syncthreads();
    int wv = t >> 6, lane = t & 63;
    int m = lane & 15, quad = lane >> 4;
    int row = blockIdx.x * 64 + wv * 16 + m;
    long rowc = (row < N) ? row : (N - 1);
    float4 f0 = *(const float4*)(x + rowc * D + quad * 8);
    float4 f1 = *(const float4*)(x + rowc * D + quad * 8 + 4);
    float4 f2 = *(const float4*)(x + rowc * D + 32 + quad * 8);
    float4 f3 = *(const float4*)(x + rowc * D + 32 + quad * 8 + 4);
    union { short8 s; uint_t u[4]; } a0, a1;
    a0.u[0] = pk_bf16(f0.x, f0.y); a0.u[1] = pk_bf16(f0.z, f0.w);
    a0.u[2] = pk_bf16(f1.x, f1.y); a0.u[3] = pk_bf16(f1.z, f1.w);
    a1.u[0] = pk_bf16(f2.x, f2.y); a1.u[1] = pk_bf16(f2.z, f2.w);
    a1.u[2] = pk_bf16(f3.x, f3.y); a1.u[3] = pk_bf16(f3.z, f3.w);
    floatx4 acc[4];
    #pragma unroll
    for (int j = 0; j < 4; ++j) {
        short8 b0 = *(short8*)&wt[(j * 16 + m) * FH + quad * 8];
        short8 b1 = *(short8*)&wt[(j * 16 + m) * FH + 32 + quad * 8];
        floatx4 z = {0.f, 0.f, 0.f, 0.f};
        acc[j] = __builtin_amdgcn_mfma_f32_16x16x32_bf16(a0.s, b0, z, 0, 0, 0);
        acc[j] = __builtin_amdgcn_mfma_f32_16x16x32_bf16(a1.s, b1, acc[j], 0, 0, 0);
    }
    int rbase = blockIdx.x * 64 + wv * 16 + quad * 4;
    #pragma unroll
    for (int r = 0; r < 4; ++r) {
        int rr = rbase + r;
        if (rr < N) {
            float sc = dis[rr];
            #pragma unroll
            for (int j = 0; j < 4; ++j)
                G[(size_t)rr * D + j * 16 + m] = rnd_bf16(acc[j][r] * sc);
        }
    }
}

// ---- gather one node's FULL edge list with an 8-lane group ----
// Uniform: segment length is a multiple of 8 (pads -> zero row N), so no
// remainder branches; indices load as int4 pairs; 8 row-gathers in flight
// per lane with next-chunk index prefetch. Edges arrive src-octant-ordered
// (k_csr) so the whole grid walks a ~2MB G window at a time.
__device__ __forceinline__ void gather_node(const ushort_t* __restrict__ G,
                                            const int* __restrict__ ssrc,
                                            int beg, int end, int c8,
                                            int node, float a[8]) {
    // self-loop contribution
    uint4 su = *(const uint4*)(G + (size_t)node * D + c8);
    a[0] = __uint_as_float(su.x << 16);
    a[1] = __uint_as_float(su.x & 0xffff0000u);
    a[2] = __uint_as_float(su.y << 16);
    a[3] = __uint_as_float(su.y & 0xffff0000u);
    a[4] = __uint_as_float(su.z << 16);
    a[5] = __uint_as_float(su.z & 0xffff0000u);
    a[6] = __uint_as_float(su.w << 16);
    a[7] = __uint_as_float(su.w & 0xffff0000u);
    #define ACCUM(u)                                                       \
        {                                                                  \
            a[0] += __uint_as_float(u.x << 16);                            \
            a[1] += __uint_as_float(u.x & 0xffff0000u);                    \
            a[2] += __uint_as_float(u.y << 16);                            \
            a[3] += __uint_as_float(u.y & 0xffff0000u);                    \
            a[4] += __uint_as_float(u.z << 16);                            \
            a[5] += __uint_as_float(u.z & 0xffff0000u);                    \
            a[6] += __uint_as_float(u.w << 16);                            \
            a[7] += __uint_as_float(u.w & 0xffff0000u);                    \
        }
    int n8 = (end - beg) >> 3;
    const int4* sp = (const int4*)(ssrc + beg);   // beg is 8-aligned
    if (n8 > 0) {
        int4 ia = sp[0], ib = sp[1];
        for (int ch = 0; ch < n8; ++ch) {
            int t0 = ia.x, t1 = ia.y, t2 = ia.z, t3 = ia.w;
            int t4 = ib.x, t5 = ib.y, t6 = ib.z, t7 = ib.w;
            if (ch + 1 < n8) { ia = sp[2 * ch + 2]; ib = sp[2 * ch + 3]; }
            uint4 u0 = *(const uint4*)(G + (size_t)t0 * D + c8);
            uint4 u1 = *(const uint4*)(G + (size_t)t1 * D + c8);
            uint4 u2 = *(const uint4*)(G + (size_t)t2 * D + c8);
            uint4 u3 = *(const uint4*)(G + (size_t)t3 * D + c8);
            uint4 u4 = *(const uint4*)(G + (size_t)t4 * D + c8);
            uint4 u5 = *(const uint4*)(G + (size_t)t5 * D + c8);
            uint4 u6 = *(const uint4*)(G + (size_t)t6 * D + c8);
            uint4 u7 = *(const uint4*)(G + (size_t)t7 * D + c8);
            ACCUM(u0); ACCUM(u1); ACCUM(u2); ACCUM(u3);
            ACCUM(u4); ACCUM(u5); ACCUM(u6); ACCUM(u7);
        }
    }
    #undef ACCUM
}

// ---------------- fused agg + next-layer MFMA gemm -----------------------
__global__ __launch_bounds__(256) void k_fagg(const ushort_t* __restrict__ G,
                                              const float* __restrict__ dis,
                                              const int2* __restrict__ rowse,
                                              const int* __restrict__ ssrc,
                                              const float* __restrict__ bias,
                                              const float* __restrict__ W,
                                              ushort_t* __restrict__ Gout,
                                              int N) {
    __shared__ ushort_t hbuf[64 * FH];
    __shared__ ushort_t wt[64 * FH];
    int t = threadIdx.x;
    stage_wt(W, wt, t);
    int wv = t >> 6, lane = t & 63;
    int g = lane >> 3;
    int c8 = (lane & 7) * 8;
    int gbase = blockIdx.x * 64;
    float4 bv0 = *(const float4*)(bias + c8);
    float4 bv1 = *(const float4*)(bias + c8 + 4);
    // phase 1: 2 iterations x 8 nodes per wave (one 8-lane group per node)
    for (int ii = 0; ii < 2; ++ii) {
        int idx = wv * 16 + ii * 8 + g;
        int node = gbase + idx;
        if (node < N) {
            int2 se = rowse[node];
            float di = dis[node];
            float a[8];
            gather_node(G, ssrc, se.x, se.y, c8, node, a);
            uint4 p;
            p.x = pk_bf16(a[0] * di + bv0.x, a[1] * di + bv0.y);
            p.y = pk_bf16(a[2] * di + bv0.z, a[3] * di + bv0.w);
            p.z = pk_bf16(a[4] * di + bv1.x, a[5] * di + bv1.y);
            p.w = pk_bf16(a[6] * di + bv1.z, a[7] * di + bv1.w);
            *(uint4*)&hbuf[idx * FH + c8] = p;
        }
    }
    __syncthreads();
    // phase 2: MFMA (layout validated R10)
    int m = lane & 15, quad = lane >> 4;
    short8 a0 = *(short8*)&hbuf[(wv * 16 + m) * FH + quad * 8];
    short8 a1 = *(short8*)&hbuf[(wv * 16 + m) * FH + 32 + quad * 8];
    floatx4 acc[4];
    #pragma unroll
    for (int j = 0; j < 4; ++j) {
        short8 b0 = *(short8*)&wt[(j * 16 + m) * FH + quad * 8];
        short8 b1 = *(short8*)&wt[(j * 16 + m) * FH + 32 + quad * 8];
        floatx4 z = {0.f, 0.f, 0.f, 0.f};
        acc[j] = __builtin_amdgcn_mfma_f32_16x16x32_bf16(a0, b0, z, 0, 0, 0);
        acc[j] = __builtin_amdgcn_mfma_f32_16x16x32_bf16(a1, b1, acc[j], 0, 0, 0);
    }
    int rbase = gbase + wv * 16 + quad * 4;
    #pragma unroll
    for (int r = 0; r < 4; ++r) {
        int row = rbase + r;
        if (row < N) {
            float sc = dis[row];
            #pragma unroll
            for (int j = 0; j < 4; ++j)
                Gout[(size_t)row * D + j * 16 + m] = rnd_bf16(acc[j][r] * sc);
        }
    }
}

// ---------------- final aggregation: out = di*(sum g) + b (fp32) ---------
// One 8-lane group per node; 32 nodes per block.
__global__ __launch_bounds__(256) void k_agg(const ushort_t* __restrict__ G,
                                             const float* __restrict__ dis,
                                             const int2* __restrict__ rowse,
                                             const int* __restrict__ ssrc,
                                             const float* __restrict__ bias,
                                             float* __restrict__ out, int N) {
    int t = threadIdx.x;
    int wv = t >> 6, lane = t & 63;
    int g = lane >> 3;
    int c8 = (lane & 7) * 8;
    int node = blockIdx.x * 32 + wv * 8 + g;
    if (node >= N) return;
    int2 se = rowse[node];
    float di = dis[node];
    float a[8];
    gather_node(G, ssrc, se.x, se.y, c8, node, a);
    float4 bv0 = *(const float4*)(bias + c8);
    float4 bv1 = *(const float4*)(bias + c8 + 4);
    float4 r0, r1;
    r0.x = a[0] * di + bv0.x; r0.y = a[1] * di + bv0.y;
    r0.z = a[2] * di + bv0.z; r0.w = a[3] * di + bv0.w;
    r1.x = a[4] * di + bv1.x; r1.y = a[5] * di + bv1.y;
    r1.z = a[6] * di + bv1.z; r1.w = a[7] * di + bv1.w;
    float4* op = (float4*)(out + (size_t)node * D + c8);
    op[0] = r0;
    op[1] = r1;
}

// ---------------- launch ----------------

extern "C" void kernel_launch(void* const* d_in, const int* in_sizes, int n_in,
                              void* d_out, int out_size, void* d_ws, size_t ws_size,
                              hipStream_t stream) {
    const float* x  = (const float*)d_in[0];
    const int*   ei = (const int*)d_in[1];
    const float* W0 = (const float*)d_in[2];
    const float* b0 = (const float*)d_in[3];
    const float* W1 = (const float*)d_in[4];
    const float* b1 = (const float*)d_in[5];
    const float* W2 = (const float*)d_in[6];
    const float* b2 = (const float*)d_in[7];
    float* out = (float*)d_out;

    const int N = in_sizes[0] / D;
    const int E = in_sizes[1] / 2;
    const int* e_src = ei;
    const int* e_dst = ei + E;

    const int nb = (N + BNODES - 1) >> RSHIFT;   // 196

    // workspace layout ((N+1) rows: row N is the zero pad row)
    size_t rowsz   = (size_t)(N + 1) * D;
    ushort_t* B0   = (ushort_t*)d_ws;                          // (N+1)*D bf16
    ushort_t* B1   = B0 + rowsz;                               // (N+1)*D bf16
    float* dis     = (float*)(B1 + rowsz);                     // N
    int2*  rowse   = (int2*)(dis + N);                         // N
    int*   ssrc    = (int*)(rowse + N);                        // nb*SCAP
    int*   bcur    = ssrc + (size_t)nb * SCAP;                 // MAXB
    int*   ebuf    = (int*)d_ws;    // nb*BCAP int = 8 MB, aliases B0 head
                                    // (dead before k_gemm0 writes B0)

    const int gG64 = (N + 63) / 64;              // 1563
    const int gAgg = (N + 31) / 32;              // 3125

    hipMemsetAsync(bcur, 0, MAXB * sizeof(int), stream);
    // zero pad-row N of both G buffers (never written by kernels)
    hipMemsetAsync(B0 + (size_t)N * D, 0, D * sizeof(ushort_t), stream);
    hipMemsetAsync(B1 + (size_t)N * D, 0, D * sizeof(ushort_t), stream);

    k_bucket<<<(E + 2047) / 2048, 256, 0, stream>>>(e_src, e_dst, bcur, ebuf, E, nb);
    k_csr<<<nb, 256, 0, stream>>>(ebuf, bcur, rowse, ssrc, dis, N, nb);

    // layer 0 gemm (MFMA, bf16 x in-register): x -> B0
    k_gemm0<<<gG64, 256, 0, stream>>>(x, W0, dis, B0, N);
    // fused agg(l0) + gemm(l1): B0 -> B1
    k_fagg<<<gG64, 256, 0, stream>>>(B0, dis, rowse, ssrc, b0, W1, B1, N);
    // fused agg(l1) + gemm(l2): B1 -> B0
    k_fagg<<<gG64, 256, 0, stream>>>(B1, dis, rowse, ssrc, b1, W2, B0, N);
    // final agg(l2): B0 -> out (fp32)
    k_agg<<<gAgg, 256, 0, stream>>>(B0, dis, rowse, ssrc, b2, out, N);
}

// Round 3
// 239.821 us; speedup vs baseline: 1.0773x; 1.0773x over previous
//
#include <hip/hip_runtime.h>
#include <hip/hip_bf16.h>

#define D 64
#define RSHIFT 9             // 512 nodes per dst-bucket
#define BNODES 512
#define MAXB 256             // >= nb = ceil(100000/512) = 196
#define BCAP 10240           // per-bucket edge capacity (mean 8192, sigma ~90)
#define SCAP 14336           // per-bucket PADDED ssrc capacity (BCAP + 512*7 pad, rounded)
#define FH 72                // LDS row stride (bf16): 144B, 4-bank skew per row

typedef unsigned short ushort_t;
typedef unsigned int uint_t;
typedef short short8 __attribute__((ext_vector_type(8)));   // 8 bf16 MFMA frag
typedef float floatx4 __attribute__((ext_vector_type(4)));  // MFMA C/D frag

__device__ inline uint_t pk_bf16(float x, float y) {
    uint_t ux = __float_as_uint(x); ux = ux + 0x7fffu + ((ux >> 16) & 1u);
    uint_t uy = __float_as_uint(y); uy = uy + 0x7fffu + ((uy >> 16) & 1u);
    return (ux >> 16) | (uy & 0xffff0000u);
}
__device__ inline ushort_t rnd_bf16(float x) {
    uint_t u = __float_as_uint(x); u = u + 0x7fffu + ((u >> 16) & 1u);
    return (ushort_t)(u >> 16);
}

// ---------------- stage 1: bucket edges by dst range ----------------
// Packed entry: (src << 9) | (dst & 511). NO per-edge global atomics (R4).
__global__ __launch_bounds__(256) void k_bucket(const int* __restrict__ src,
                                                const int* __restrict__ dst,
                                                int* __restrict__ bcur,
                                                int* __restrict__ ebuf,
                                                int E, int nb) {
    __shared__ int lcnt[MAXB];
    __shared__ int lbase[MAXB];
    int t = threadIdx.x;
    lcnt[t] = 0;
    __syncthreads();
    int base = blockIdx.x * 2048 + t * 8;
    int sv[8], dv[8], sl[8];
    if (base + 7 < E) {
        int4 a0 = *(const int4*)(src + base);
        int4 a1 = *(const int4*)(src + base + 4);
        int4 b0 = *(const int4*)(dst + base);
        int4 b1 = *(const int4*)(dst + base + 4);
        sv[0]=a0.x; sv[1]=a0.y; sv[2]=a0.z; sv[3]=a0.w;
        sv[4]=a1.x; sv[5]=a1.y; sv[6]=a1.z; sv[7]=a1.w;
        dv[0]=b0.x; dv[1]=b0.y; dv[2]=b0.z; dv[3]=b0.w;
        dv[4]=b1.x; dv[5]=b1.y; dv[6]=b1.z; dv[7]=b1.w;
    } else {
        #pragma unroll
        for (int j = 0; j < 8; ++j) {
            dv[j] = (base + j < E) ? dst[base + j] : -1;
            sv[j] = (base + j < E) ? src[base + j] : 0;
        }
    }
    #pragma unroll
    for (int j = 0; j < 8; ++j) {
        if (dv[j] >= 0) {
            int b = dv[j] >> RSHIFT;
            sl[j] = atomicAdd(&lcnt[b], 1);   // LDS atomic only
        }
    }
    __syncthreads();
    if (t < nb) { int c = lcnt[t]; if (c) lbase[t] = atomicAdd(&bcur[t], c); }
    __syncthreads();
    #pragma unroll
    for (int j = 0; j < 8; ++j) {
        if (dv[j] >= 0) {
            int b = dv[j] >> RSHIFT;
            int slot = lbase[b] + sl[j];
            if (slot < BCAP)
                ebuf[(size_t)b * BCAP + slot] = (sv[j] << RSHIFT) | (dv[j] & (BNODES - 1));
        }
    }
}

// ---------------- stage 2: per-bucket CSR build, all atomics in LDS -------
// Fixed per-bucket ssrc region (b*SCAP); per-node segments padded to x8
// (pads -> zero row N) so the gather loop is branch-free with int4 index
// loads. Octant ordering REVERTED (R2: neutral gather, +4us csr).
__global__ __launch_bounds__(256) void k_csr(const int* __restrict__ ebuf,
                                             const int* __restrict__ bcur,
                                             int2* __restrict__ rowse,
                                             int* __restrict__ ssrc,
                                             float* __restrict__ dis,
                                             int N, int nb) {
    __shared__ int sseg[BCAP];        // 40 KB edge stage
    __shared__ int lcnt[BNODES];
    __shared__ int lcur[BNODES];
    __shared__ int sums[256];
    int b = blockIdx.x;
    int t = threadIdx.x;
    int n = bcur[b];
    if (n > BCAP) n = BCAP;
    int node0 = b << RSHIFT;
    #pragma unroll
    for (int i = t; i < BNODES; i += 256) lcnt[i] = 0;
    __syncthreads();
    const int* seg = ebuf + (size_t)b * BCAP;
    // count + stage edges into LDS
    for (int i = t * 4; i < n; i += 1024) {
        if (i + 3 < n) {
            int4 e = *(const int4*)(seg + i);
            *(int4*)(sseg + i) = e;
            atomicAdd(&lcnt[e.x & (BNODES - 1)], 1);
            atomicAdd(&lcnt[e.y & (BNODES - 1)], 1);
            atomicAdd(&lcnt[e.z & (BNODES - 1)], 1);
            atomicAdd(&lcnt[e.w & (BNODES - 1)], 1);
        } else {
            for (int j = 0; j < 4 && i + j < n; ++j) {
                int e = seg[i + j];
                sseg[i + j] = e;
                atomicAdd(&lcnt[e & (BNODES - 1)], 1);
            }
        }
    }
    __syncthreads();
    int idx = t * 2;
    int v0 = lcnt[idx], v1 = lcnt[idx + 1];
    int p0 = (v0 + 7) & ~7;           // padded lengths
    int p1 = (v1 + 7) & ~7;
    int s = p0 + p1;
    sums[t] = s;
    __syncthreads();
    for (int off = 1; off < 256; off <<= 1) {
        int x = (t >= off) ? sums[t - off] : 0;
        __syncthreads();
        sums[t] += x;
        __syncthreads();
    }
    int run = sums[t] - s;
    int beg0 = b * SCAP + run;
    int beg1 = beg0 + p0;
    lcur[idx] = beg0;
    lcur[idx + 1] = beg1;
    int node = node0 + idx;
    if (node < N)     { rowse[node]     = make_int2(beg0, beg0 + p0); dis[node]     = rsqrtf((float)(v0 + 1)); }
    if (node + 1 < N) { rowse[node + 1] = make_int2(beg1, beg1 + p1); dis[node + 1] = rsqrtf((float)(v1 + 1)); }
    __syncthreads();
    // single scatter pass from LDS stage
    for (int i = t * 4; i < n; i += 1024) {
        if (i + 3 < n) {
            int4 e = *(const int4*)(sseg + i);
            int q0 = atomicAdd(&lcur[e.x & (BNODES - 1)], 1); ssrc[q0] = e.x >> RSHIFT;
            int q1 = atomicAdd(&lcur[e.y & (BNODES - 1)], 1); ssrc[q1] = e.y >> RSHIFT;
            int q2 = atomicAdd(&lcur[e.z & (BNODES - 1)], 1); ssrc[q2] = e.z >> RSHIFT;
            int q3 = atomicAdd(&lcur[e.w & (BNODES - 1)], 1); ssrc[q3] = e.w >> RSHIFT;
        } else {
            for (int j = 0; j < 4 && i + j < n; ++j) {
                int e = sseg[i + j];
                int q = atomicAdd(&lcur[e & (BNODES - 1)], 1); ssrc[q] = e >> RSHIFT;
            }
        }
    }
    // fill pads with zero-row index N
    for (int k = v0; k < p0; ++k) ssrc[beg0 + k] = N;
    for (int k = v1; k < p1; ++k) ssrc[beg1 + k] = N;
}

// stage W^T as bf16 into LDS: wt[n][k] = bf16(W[k][n]) (validated R10)
__device__ __forceinline__ void stage_wt(const float* __restrict__ W,
                                         ushort_t* __restrict__ wt, int t) {
    const float4* W4 = (const float4*)W;
    for (int i = t; i < 1024; i += 256) {
        float4 w4 = W4[i];
        int k = i >> 4, n0 = (i & 15) * 4;
        wt[(n0 + 0) * FH + k] = rnd_bf16(w4.x);
        wt[(n0 + 1) * FH + k] = rnd_bf16(w4.y);
        wt[(n0 + 2) * FH + k] = rnd_bf16(w4.z);
        wt[(n0 + 3) * FH + k] = rnd_bf16(w4.w);
    }
}

// ---------------- layer-0 GEMM via MFMA: G = bf16((x@W)*dis) -------------
__global__ __launch_bounds__(256) void k_gemm0(const float* __restrict__ x,
                                               const float* __restrict__ W,
                                               const float* __restrict__ dis,
                                               ushort_t* __restrict__ G, int N) {
    __shared__ ushort_t wt[64 * FH];
    int t = threadIdx.x;
    stage_wt(W, wt, t);
    __syncthreads();
    int wv = t >> 6, lane = t & 63;
    int m = lane & 15, quad = lane >> 4;
    int row = blockIdx.x * 64 + wv * 16 + m;
    long rowc = (row < N) ? row : (N - 1);
    float4 f0 = *(const float4*)(x + rowc * D + quad * 8);
    float4 f1 = *(const float4*)(x + rowc * D + quad * 8 + 4);
    float4 f2 = *(const float4*)(x + rowc * D + 32 + quad * 8);
    float4 f3 = *(const float4*)(x + rowc * D + 32 + quad * 8 + 4);
    union { short8 s; uint_t u[4]; } a0, a1;
    a0.u[0] = pk_bf16(f0.x, f0.y); a0.u[1] = pk_bf16(f0.z, f0.w);
    a0.u[2] = pk_bf16(f1.x, f1.y); a0.u[3] = pk_bf16(f1.z, f1.w);
    a1.u[0] = pk_bf16(f2.x, f2.y); a1.u[1] = pk_bf16(f2.z, f2.w);
    a1.u[2] = pk_bf16(f3.x, f3.y); a1.u[3] = pk_bf16(f3.z, f3.w);
    floatx4 acc[4];
    #pragma unroll
    for (int j = 0; j < 4; ++j) {
        short8 b0 = *(short8*)&wt[(j * 16 + m) * FH + quad * 8];
        short8 b1 = *(short8*)&wt[(j * 16 + m) * FH + 32 + quad * 8];
        floatx4 z = {0.f, 0.f, 0.f, 0.f};
        acc[j] = __builtin_amdgcn_mfma_f32_16x16x32_bf16(a0.s, b0, z, 0, 0, 0);
        acc[j] = __builtin_amdgcn_mfma_f32_16x16x32_bf16(a1.s, b1, acc[j], 0, 0, 0);
    }
    int rbase = blockIdx.x * 64 + wv * 16 + quad * 4;
    #pragma unroll
    for (int r = 0; r < 4; ++r) {
        int rr = rbase + r;
        if (rr < N) {
            float sc = dis[rr];
            #pragma unroll
            for (int j = 0; j < 4; ++j)
                G[(size_t)rr * D + j * 16 + m] = rnd_bf16(acc[j][r] * sc);
        }
    }
}

// ---- gather one node's FULL edge list with an 8-lane group ----
// Software-pipelined: chunk c+1's 8 row-loads are issued BEFORE chunk c's
// ACCUM (R2 post-mortem: gather is latency-bound; the old loop drained all
// loads before accumulating -> ~3 serialized full-latency stalls per node).
// Indices are prefetched one chunk ahead so row-loads issue immediately.
// Segment length is a multiple of 8 (pads -> zero row N): branch-free.
// Self-loop row is loaded first but accumulated LAST (latency hidden).
__device__ __forceinline__ void gather_node(const ushort_t* __restrict__ G,
                                            const int* __restrict__ ssrc,
                                            int beg, int end, int c8,
                                            int node, float a[8]) {
    #pragma unroll
    for (int j = 0; j < 8; ++j) a[j] = 0.f;
    #define ROW(i) (*(const uint4*)(G + (size_t)(i) * D + c8))
    #define ACC1(u)                                                        \
        {                                                                  \
            a[0] += __uint_as_float(u.x << 16);                            \
            a[1] += __uint_as_float(u.x & 0xffff0000u);                    \
            a[2] += __uint_as_float(u.y << 16);                            \
            a[3] += __uint_as_float(u.y & 0xffff0000u);                    \
            a[4] += __uint_as_float(u.z << 16);                            \
            a[5] += __uint_as_float(u.z & 0xffff0000u);                    \
            a[6] += __uint_as_float(u.w << 16);                            \
            a[7] += __uint_as_float(u.w & 0xffff0000u);                    \
        }
    uint4 su = ROW(node);
    int n8 = (end - beg) >> 3;
    const int4* sp = (const int4*)(ssrc + beg);   // beg is 8-aligned (32B)
    if (n8 > 0) {
        int4 ia = sp[0], ib = sp[1];
        uint4 u0 = ROW(ia.x), u1 = ROW(ia.y), u2 = ROW(ia.z), u3 = ROW(ia.w);
        uint4 u4 = ROW(ib.x), u5 = ROW(ib.y), u6 = ROW(ib.z), u7 = ROW(ib.w);
        if (n8 > 1) { ia = sp[2]; ib = sp[3]; }
        for (int ch = 1; ch < n8; ++ch) {
            uint4 v0 = ROW(ia.x), v1 = ROW(ia.y), v2 = ROW(ia.z), v3 = ROW(ia.w);
            uint4 v4 = ROW(ib.x), v5 = ROW(ib.y), v6 = ROW(ib.z), v7 = ROW(ib.w);
            if (ch + 1 < n8) { ia = sp[2 * ch + 2]; ib = sp[2 * ch + 3]; }
            ACC1(u0); ACC1(u1); ACC1(u2); ACC1(u3);
            ACC1(u4); ACC1(u5); ACC1(u6); ACC1(u7);
            u0 = v0; u1 = v1; u2 = v2; u3 = v3;
            u4 = v4; u5 = v5; u6 = v6; u7 = v7;
        }
        ACC1(u0); ACC1(u1); ACC1(u2); ACC1(u3);
        ACC1(u4); ACC1(u5); ACC1(u6); ACC1(u7);
    }
    ACC1(su);   // self-loop last: its load latency hid under the chunks
    #undef ACC1
    #undef ROW
}

// ---------------- fused agg + next-layer MFMA gemm -----------------------
__global__ __launch_bounds__(256) void k_fagg(const ushort_t* __restrict__ G,
                                              const float* __restrict__ dis,
                                              const int2* __restrict__ rowse,
                                              const int* __restrict__ ssrc,
                                              const float* __restrict__ bias,
                                              const float* __restrict__ W,
                                              ushort_t* __restrict__ Gout,
                                              int N) {
    __shared__ ushort_t hbuf[64 * FH];
    __shared__ ushort_t wt[64 * FH];
    int t = threadIdx.x;
    stage_wt(W, wt, t);
    int wv = t >> 6, lane = t & 63;
    int g = lane >> 3;
    int c8 = (lane & 7) * 8;
    int gbase = blockIdx.x * 64;
    float4 bv0 = *(const float4*)(bias + c8);
    float4 bv1 = *(const float4*)(bias + c8 + 4);
    // phase 1: 2 iterations x 8 nodes per wave (one 8-lane group per node)
    for (int ii = 0; ii < 2; ++ii) {
        int idx = wv * 16 + ii * 8 + g;
        int node = gbase + idx;
        if (node < N) {
            int2 se = rowse[node];
            float di = dis[node];
            float a[8];
            gather_node(G, ssrc, se.x, se.y, c8, node, a);
            uint4 p;
            p.x = pk_bf16(a[0] * di + bv0.x, a[1] * di + bv0.y);
            p.y = pk_bf16(a[2] * di + bv0.z, a[3] * di + bv0.w);
            p.z = pk_bf16(a[4] * di + bv1.x, a[5] * di + bv1.y);
            p.w = pk_bf16(a[6] * di + bv1.z, a[7] * di + bv1.w);
            *(uint4*)&hbuf[idx * FH + c8] = p;
        }
    }
    __syncthreads();
    // phase 2: MFMA (layout validated R10)
    int m = lane & 15, quad = lane >> 4;
    short8 a0 = *(short8*)&hbuf[(wv * 16 + m) * FH + quad * 8];
    short8 a1 = *(short8*)&hbuf[(wv * 16 + m) * FH + 32 + quad * 8];
    floatx4 acc[4];
    #pragma unroll
    for (int j = 0; j < 4; ++j) {
        short8 b0 = *(short8*)&wt[(j * 16 + m) * FH + quad * 8];
        short8 b1 = *(short8*)&wt[(j * 16 + m) * FH + 32 + quad * 8];
        floatx4 z = {0.f, 0.f, 0.f, 0.f};
        acc[j] = __builtin_amdgcn_mfma_f32_16x16x32_bf16(a0, b0, z, 0, 0, 0);
        acc[j] = __builtin_amdgcn_mfma_f32_16x16x32_bf16(a1, b1, acc[j], 0, 0, 0);
    }
    int rbase = gbase + wv * 16 + quad * 4;
    #pragma unroll
    for (int r = 0; r < 4; ++r) {
        int row = rbase + r;
        if (row < N) {
            float sc = dis[row];
            #pragma unroll
            for (int j = 0; j < 4; ++j)
                Gout[(size_t)row * D + j * 16 + m] = rnd_bf16(acc[j][r] * sc);
        }
    }
}

// ---------------- final aggregation: out = di*(sum g) + b (fp32) ---------
// One 8-lane group per node; 32 nodes per block.
__global__ __launch_bounds__(256) void k_agg(const ushort_t* __restrict__ G,
                                             const float* __restrict__ dis,
                                             const int2* __restrict__ rowse,
                                             const int* __restrict__ ssrc,
                                             const float* __restrict__ bias,
                                             float* __restrict__ out, int N) {
    int t = threadIdx.x;
    int wv = t >> 6, lane = t & 63;
    int g = lane >> 3;
    int c8 = (lane & 7) * 8;
    int node = blockIdx.x * 32 + wv * 8 + g;
    if (node >= N) return;
    int2 se = rowse[node];
    float di = dis[node];
    float a[8];
    gather_node(G, ssrc, se.x, se.y, c8, node, a);
    float4 bv0 = *(const float4*)(bias + c8);
    float4 bv1 = *(const float4*)(bias + c8 + 4);
    float4 r0, r1;
    r0.x = a[0] * di + bv0.x; r0.y = a[1] * di + bv0.y;
    r0.z = a[2] * di + bv0.z; r0.w = a[3] * di + bv0.w;
    r1.x = a[4] * di + bv1.x; r1.y = a[5] * di + bv1.y;
    r1.z = a[6] * di + bv1.z; r1.w = a[7] * di + bv1.w;
    float4* op = (float4*)(out + (size_t)node * D + c8);
    op[0] = r0;
    op[1] = r1;
}

// ---------------- launch ----------------

extern "C" void kernel_launch(void* const* d_in, const int* in_sizes, int n_in,
                              void* d_out, int out_size, void* d_ws, size_t ws_size,
                              hipStream_t stream) {
    const float* x  = (const float*)d_in[0];
    const int*   ei = (const int*)d_in[1];
    const float* W0 = (const float*)d_in[2];
    const float* b0 = (const float*)d_in[3];
    const float* W1 = (const float*)d_in[4];
    const float* b1 = (const float*)d_in[5];
    const float* W2 = (const float*)d_in[6];
    const float* b2 = (const float*)d_in[7];
    float* out = (float*)d_out;

    const int N = in_sizes[0] / D;
    const int E = in_sizes[1] / 2;
    const int* e_src = ei;
    const int* e_dst = ei + E;

    const int nb = (N + BNODES - 1) >> RSHIFT;   // 196

    // workspace layout ((N+1) rows: row N is the zero pad row)
    size_t rowsz   = (size_t)(N + 1) * D;
    ushort_t* B0   = (ushort_t*)d_ws;                          // (N+1)*D bf16
    ushort_t* B1   = B0 + rowsz;                               // (N+1)*D bf16
    float* dis     = (float*)(B1 + rowsz);                     // N
    int2*  rowse   = (int2*)(dis + N);                         // N
    int*   ssrc    = (int*)(rowse + N);                        // nb*SCAP
    int*   bcur    = ssrc + (size_t)nb * SCAP;                 // MAXB
    int*   ebuf    = (int*)d_ws;    // nb*BCAP int = 8 MB, aliases B0 head
                                    // (dead before k_gemm0 writes B0)

    const int gG64 = (N + 63) / 64;              // 1563
    const int gAgg = (N + 31) / 32;              // 3125

    hipMemsetAsync(bcur, 0, MAXB * sizeof(int), stream);
    // zero pad-row N of both G buffers (never written by kernels)
    hipMemsetAsync(B0 + (size_t)N * D, 0, D * sizeof(ushort_t), stream);
    hipMemsetAsync(B1 + (size_t)N * D, 0, D * sizeof(ushort_t), stream);

    k_bucket<<<(E + 2047) / 2048, 256, 0, stream>>>(e_src, e_dst, bcur, ebuf, E, nb);
    k_csr<<<nb, 256, 0, stream>>>(ebuf, bcur, rowse, ssrc, dis, N, nb);

    // layer 0 gemm (MFMA, bf16 x in-register): x -> B0
    k_gemm0<<<gG64, 256, 0, stream>>>(x, W0, dis, B0, N);
    // fused agg(l0) + gemm(l1): B0 -> B1
    k_fagg<<<gG64, 256, 0, stream>>>(B0, dis, rowse, ssrc, b0, W1, B1, N);
    // fused agg(l1) + gemm(l2): B1 -> B0
    k_fagg<<<gG64, 256, 0, stream>>>(B1, dis, rowse, ssrc, b1, W2, B0, N);
    // final agg(l2): B0 -> out (fp32)
    k_agg<<<gAgg, 256, 0, stream>>>(B0, dis, rowse, ssrc, b2, out, N);
}